// Round 8
// baseline (3041.991 us; speedup 1.0000x reference)
//
#include <hip/hip_runtime.h>
#include <hip/hip_bf16.h>

// RNN: outs[t] = h_t = tanh(x[t]@Wx + b + h_{t-1}@Wh), T=512,B=64,IN=512,H=1024
//  - split-bf16 (hi+lo) MFMA everywhere (no fp32 MFMA on CDNA4); 3-term product
//  - phase A: xw = x@Wx+b written directly into d_out (overwritten by h_t in place)
//  - scan: 128 persistent wgs = 4 batch-groups(16 rows) x 32 col-groups(32 cols),
//    Wh register-resident, self-validating tagged-f32 h (low 7 mantissa bits =
//    epoch tag 64|(t&63); the poll IS the data load).
//  - R1 coherent-h only: 15.5->9.5 us/step. R2 flag barrier: REGRESSED.
//  - R3 self-validating h: ->6.4. R4 XCD-local: DEADLOCK (lesson: polled bytes
//    must use architecturally-coherent ops). R5 swap-RMW+chunk retries: ->5.9.
//  - R6 group-packed col-major layout [g][par][1024k][16r] (contiguous poll
//    loads, 4 lines/instr) + LDS bounce for fragment transpose: ->4.6.
//  - R7: CHUNK-PIPELINED POLL. Chunks (8-k x 16r, one producer wg each) are
//    bounced to LDS and their kt-blocks MFMA'd AS THEY VALIDATE, inside the
//    poll loop; convert+MFMA of early arrivals hides under polling for late
//    ones; serial tail after last chunk ~= one bounce + 1 kt + epilogue.
//    Producer h-store issued before out stores/prefetch. Sleep only on idle
//    sweeps. All masks wave-uniform; LDS band wave-private (no new syncs).

#define T_ 512
#define B_ 64
#define IN_ 512
#define H_ 1024
constexpr int TBH = T_ * B_ * H_;   // 33,554,432
constexpr int HB  = B_ * H_;        // 65,536
constexpr int GP  = 1024 * 16;      // u32s per (group,parity) packed slice

typedef unsigned short u16;
typedef unsigned int u32;
typedef unsigned long long u64;
typedef __attribute__((ext_vector_type(8))) short short8;   // 8 x bf16 (4 VGPRs)
typedef __attribute__((ext_vector_type(4))) float f32x4;

__device__ __forceinline__ void splitbf(float x, u16& hi, u16& lo) {
    unsigned u = __float_as_uint(x);
    hi = (u16)(u >> 16);                       // truncated bf16 hi
    float r = x - __uint_as_float(u & 0xffff0000u);
    lo = (u16)(__float_as_uint(r) >> 16);      // bf16 of residual; total rel err ~2^-16
}

// ---- prep kernels ------------------------------------------------------------
__global__ void k_split4(const float4* __restrict__ in, u16* __restrict__ hi,
                         u16* __restrict__ lo, int n4) {
    int i = blockIdx.x * blockDim.x + threadIdx.x;
    int stride = gridDim.x * blockDim.x;
    for (; i < n4; i += stride) {
        float4 v = in[i];
        u16 h0,h1,h2,h3,l0,l1,l2,l3;
        splitbf(v.x,h0,l0); splitbf(v.y,h1,l1); splitbf(v.z,h2,l2); splitbf(v.w,h3,l3);
        uint2 hv, lv;
        hv.x = (unsigned)h0 | ((unsigned)h1 << 16);
        hv.y = (unsigned)h2 | ((unsigned)h3 << 16);
        lv.x = (unsigned)l0 | ((unsigned)l1 << 16);
        lv.y = (unsigned)l2 | ((unsigned)l3 << 16);
        *(uint2*)&hi[4*i] = hv;
        *(uint2*)&lo[4*i] = lv;
    }
}

// src [K][N] fp32 -> dst [N][K] bf16 hi/lo (transposed for B-fragment reads)
__global__ void k_tsplit(const float* __restrict__ src, u16* __restrict__ hi,
                         u16* __restrict__ lo, int K, int N) {
    int id = blockIdx.x * 256 + threadIdx.x;
    if (id >= K * N) return;
    int k = id / N, n = id % N;
    u16 h, l; splitbf(src[id], h, l);
    hi[n*K + k] = h; lo[n*K + k] = l;
}

// h0 fp32 [B][H] -> packed tagged-f32 parity-1 (read at t=0, expects tag 127)
__global__ void k_h0(const float* __restrict__ h0, u32* __restrict__ hbufP) {
    int id = blockIdx.x * 256 + threadIdx.x;
    if (id >= HB) return;
    int b = id >> 10, k = id & 1023;
    u32 u = __float_as_uint(h0[id]);
    hbufP[(size_t)((b>>4)*2 + 1)*GP + k*16 + (b & 15)] = (u & 0xFFFFFF80u) | 127u;
}

// ---- phase A: xw = x@Wx + b, split-bf16 MFMA, 128x128 tile, frags from global -
__launch_bounds__(256, 2)
__global__ void k_gemm_xw(const u16* __restrict__ xhi, const u16* __restrict__ xlo,
                          const u16* __restrict__ wthi, const u16* __restrict__ wtlo,
                          const float* __restrict__ bias, float* __restrict__ out) {
    int bid = blockIdx.x;
    int mi = bid >> 3, ni = bid & 7;
    int m0 = mi * 128, n0 = ni * 128;
    int wave = threadIdx.x >> 6, lane = threadIdx.x & 63;
    int wr = wave >> 1, wc = wave & 1;
    int lrow = lane & 15, lk8 = (lane >> 4) * 8;
    const int rowb = m0 + wr*64 + lrow;   // A row for this lane
    const int colb = n0 + wc*64 + lrow;   // B col for this lane
    f32x4 acc[4][4] = {};
    for (int kt = 0; kt < 16; ++kt) {
        int kb = kt*32 + lk8;
        short8 ah[4], al[4], bh[4], bl[4];
#pragma unroll
        for (int mt = 0; mt < 4; ++mt) {
            ah[mt] = *(const short8*)&xhi[(size_t)(rowb + mt*16)*IN_ + kb];
            al[mt] = *(const short8*)&xlo[(size_t)(rowb + mt*16)*IN_ + kb];
        }
#pragma unroll
        for (int nt = 0; nt < 4; ++nt) {
            bh[nt] = *(const short8*)&wthi[(size_t)(colb + nt*16)*IN_ + kb];
            bl[nt] = *(const short8*)&wtlo[(size_t)(colb + nt*16)*IN_ + kb];
        }
#pragma unroll
        for (int mt = 0; mt < 4; ++mt)
#pragma unroll
            for (int nt = 0; nt < 4; ++nt) {
                acc[mt][nt] = __builtin_amdgcn_mfma_f32_16x16x32_bf16(ah[mt], bh[nt], acc[mt][nt], 0,0,0);
                acc[mt][nt] = __builtin_amdgcn_mfma_f32_16x16x32_bf16(ah[mt], bl[nt], acc[mt][nt], 0,0,0);
                acc[mt][nt] = __builtin_amdgcn_mfma_f32_16x16x32_bf16(al[mt], bh[nt], acc[mt][nt], 0,0,0);
            }
    }
    // epilogue: D layout col=lane&15, row=4*(lane>>4)+reg
    int orow0 = m0 + wr*64 + 4*(lane >> 4);
#pragma unroll
    for (int nt = 0; nt < 4; ++nt) {
        int col = n0 + wc*64 + nt*16 + (lane & 15);
        float bv = bias[col];
#pragma unroll
        for (int mt = 0; mt < 4; ++mt)
#pragma unroll
            for (int r = 0; r < 4; ++r)
                out[(size_t)(orow0 + mt*16 + r)*H_ + col] = acc[mt][nt][r] + bv;
    }
}

// ---- phase A fallback (fp32 vector) if ws too small for split buffers --------
__global__ void k_gemm_f32(const float* __restrict__ A, const float* __restrict__ Bw,
                           const float* __restrict__ bias, float* __restrict__ out) {
    __shared__ float As[32][65];  // [k][m]
    __shared__ float Bs[32][65];  // [k][n]
    int n0 = blockIdx.x * 64, m0 = blockIdx.y * 64;
    int tid = threadIdx.x;
    int tr = tid >> 4, tc = tid & 15;
    float acc[4][4] = {};
    for (int kc = 0; kc < IN_; kc += 32) {
#pragma unroll
        for (int it = 0; it < 8; ++it) {
            int id = tid + 256*it;
            int k = id & 31, m = id >> 5;
            As[k][m] = A[(size_t)(m0 + m)*IN_ + kc + k];
        }
#pragma unroll
        for (int it = 0; it < 8; ++it) {
            int id = tid + 256*it;
            int n = id & 63, kk = id >> 6;
            Bs[kk][n] = Bw[(size_t)(kc + kk)*H_ + n0 + n];
        }
        __syncthreads();
#pragma unroll
        for (int kk = 0; kk < 32; ++kk) {
            float a[4], b[4];
#pragma unroll
            for (int i = 0; i < 4; ++i) a[i] = As[kk][tr*4+i];
#pragma unroll
            for (int j = 0; j < 4; ++j) b[j] = Bs[kk][tc*4+j];
#pragma unroll
            for (int i = 0; i < 4; ++i)
#pragma unroll
                for (int j = 0; j < 4; ++j) acc[i][j] += a[i]*b[j];
        }
        __syncthreads();
    }
#pragma unroll
    for (int i = 0; i < 4; ++i)
#pragma unroll
        for (int j = 0; j < 4; ++j)
            out[(size_t)(m0 + tr*4 + i)*H_ + n0 + tc*4 + j] = acc[i][j] + bias[n0 + tc*4 + j];
}

// ---- scan: persistent, Wh register-resident, chunk-pipelined poll ------------
__launch_bounds__(256, 1)
__global__ void k_scan(const float* __restrict__ wh,   // [H][H] fp32 (k-major)
                       float* __restrict__ out,        // [T][B][H] xw in / h out, + h_last tail
                       u32* __restrict__ hbufP) {      // [4 g][2 par][1024 k][16 r] tagged f32
    int bid = blockIdx.x;
    int g = bid >> 5, cg = bid & 31;
    int n0 = cg * 32;
    int row_g = g * 16;
    int wave = threadIdx.x >> 6, lane = threadIdx.x & 63;
    int lrow = lane & 15, lk8 = (lane >> 4) * 8;
    __shared__ float partial[2 * 4 * 16 * 33];   // [parity][wave][row][col(+pad)]
    __shared__ float hx[16 * 1030];              // [row][k] bounce, stride 1030 (wave-private bands)

    // Load Wh fragments ONCE: this wave covers k in [wave*256, wave*256+256)
    short8 bh[2][8], bl[2][8];
#pragma unroll
    for (int nt = 0; nt < 2; ++nt) {
        int col = n0 + nt*16 + lrow;
#pragma unroll
        for (int kt = 0; kt < 8; ++kt) {
            int kbase = wave*256 + kt*32 + lk8;
            short8 h8, l8;
#pragma unroll
            for (int j = 0; j < 8; ++j) {
                u16 hh, ll; splitbf(wh[(size_t)(kbase + j)*H_ + col], hh, ll);
                h8[j] = (short)hh; l8[j] = (short)ll;
            }
            bh[nt][kt] = h8; bl[nt][kt] = l8;
        }
    }

    // epilogue mapping: thread = (col ec, row-pair er0)
    const int ec  = threadIdx.x >> 3;        // 0..31 wg-local col
    const int er0 = (threadIdx.x & 7) * 2;   // 0,2,..,14 group-local row

    // prefetch xw for t=0 (rows er0, er0+1 of col n0+ec)
    float xw0 = out[(size_t)(row_g + er0    )*H_ + n0 + ec];
    float xw1 = out[(size_t)(row_g + er0 + 1)*H_ + n0 + ec];

    // bounce indexing: u64 #(i*64+lane) = k_local i*8+(lane>>3), rows 2*(lane&7),+1
    const int bcol = wave*256 + (lane >> 3);
    const int brow = 2 * (lane & 7);

    for (int t = 0; t < T_; ++t) {
        const u32 want = 64u | (u32)((t - 1) & 63);
        const u64 want64 = ((u64)want << 32) | (u64)want;
        const int par = t & 1;
        const u64* sb = (const u64*)(hbufP + (size_t)(g*2 + ((t+1)&1))*GP) + wave*2048;

        // ---- chunk-pipelined poll: validate -> bounce -> MFMA inside the loop
        u64 raw[32];
        f32x4 acc[2][2] = {};
        u32 pend = 0xFFFFFFFFu;   // chunks not yet validated (wave-uniform)
        u32 vmask = 0;            // chunks bounced to LDS
        u32 ktdone = 0;           // kt blocks already MFMA'd (8 bits)
        for (;;) {
            // load pending chunks (contiguous 512B per instr = 4 lines)
#pragma unroll
            for (int i = 0; i < 32; ++i)
                if (pend & (1u << i))
                    raw[i] = __hip_atomic_load(sb + i*64 + lane, __ATOMIC_RELAXED,
                                               __HIP_MEMORY_SCOPE_AGENT);
            // validate
            u32 np = 0;
#pragma unroll
            for (int i = 0; i < 32; ++i)
                if (pend & (1u << i)) {
                    u64 bad = (raw[i] ^ want64) & 0x0000007F0000007FULL;
                    if (__any(bad != 0)) np |= 1u << i;
                }
            u32 newly = pend & ~np;
            pend = np;
            // bounce newly-valid chunks to LDS (wave-private band; compiler
            // inserts the lgkmcnt ordering for the reads below)
#pragma unroll
            for (int i = 0; i < 32; ++i)
                if (newly & (1u << i)) {
                    int col = bcol + i*8;
                    hx[brow*1030 + col]     = __uint_as_float((u32)raw[i]);
                    hx[(brow+1)*1030 + col] = __uint_as_float((u32)(raw[i] >> 32));
                }
            vmask |= newly;
            // fire kt blocks whose 4 chunks are all resident
#pragma unroll
            for (int kt = 0; kt < 8; ++kt) {
                if (!(ktdone & (1u << kt)) && ((vmask >> (4*kt)) & 0xFu) == 0xFu) {
                    ktdone |= 1u << kt;
                    int p = kt & 1;
                    short8 ah, al;
                    int cb = lrow*1030 + wave*256 + kt*32 + lk8;
#pragma unroll
                    for (int j = 0; j < 8; ++j) {
                        u32 bits = __float_as_uint(hx[cb + j]);
                        ah[j] = (short)(bits >> 16);
                        float r = __uint_as_float(bits & 0xFFFFFF80u)
                                - __uint_as_float(bits & 0xFFFF0000u);
                        al[j] = (short)(__float_as_uint(r) >> 16);
                    }
#pragma unroll
                    for (int nt = 0; nt < 2; ++nt) {
                        acc[nt][p] = __builtin_amdgcn_mfma_f32_16x16x32_bf16(ah, bh[nt][kt], acc[nt][p], 0,0,0);
                        acc[nt][p] = __builtin_amdgcn_mfma_f32_16x16x32_bf16(ah, bl[nt][kt], acc[nt][p], 0,0,0);
                        acc[nt][p] = __builtin_amdgcn_mfma_f32_16x16x32_bf16(al, bh[nt][kt], acc[nt][p], 0,0,0);
                    }
                }
            }
            if (ktdone == 0xFFu) break;
            if (newly == 0) __builtin_amdgcn_s_sleep(1);
        }

        // K-partials to LDS (parity dbuf): row=4*(lane>>4)+r, col=nt*16+lrow
        {
            int r0 = 4 * (lane >> 4);
#pragma unroll
            for (int nt = 0; nt < 2; ++nt) {
                int c = nt*16 + lrow;
#pragma unroll
                for (int r = 0; r < 4; ++r)
                    partial[((par*4 + wave)*16 + r0 + r)*33 + c] = acc[nt][0][r] + acc[nt][1][r];
            }
        }
        __syncthreads();
        // ---- reduce + tanh; h-store FIRST (exchange-critical), then out ----
        {
            float s0 = xw0, s1 = xw1;
#pragma unroll
            for (int w = 0; w < 4; ++w) {
                s0 += partial[((par*4 + w)*16 + er0    )*33 + ec];
                s1 += partial[((par*4 + w)*16 + er0 + 1)*33 + ec];
            }
            float y0 = tanhf(s0), y1 = tanhf(s1);
            const u32 tagt = 64u | (u32)(t & 63);
            u32 b0 = (__float_as_uint(y0) & 0xFFFFFF80u) | tagt;
            u32 b1 = (__float_as_uint(y1) & 0xFFFFFF80u) | tagt;
            // packed [col][row-pair] -> one contiguous u64 swap (RMW at coherence pt)
            u32* hnb = hbufP + (size_t)(g*2 + par)*GP + (n0 + ec)*16 + er0;
            (void)__hip_atomic_exchange((u64*)hnb, ((u64)b1 << 32) | (u64)b0,
                                        __ATOMIC_RELAXED, __HIP_MEMORY_SCOPE_AGENT);
            int gb0 = row_g + er0;
            out[(size_t)(t*B_ + gb0    )*H_ + n0 + ec] = y0;
            out[(size_t)(t*B_ + gb0 + 1)*H_ + n0 + ec] = y1;
            if (t == T_-1) {
                out[(size_t)TBH + (size_t)gb0*H_ + n0 + ec] = y0;
                out[(size_t)TBH + (size_t)(gb0+1)*H_ + n0 + ec] = y1;
            }
        }
        // prefetch next xw (latency hides under next step's h polling)
        if (t + 1 < T_) {
            xw0 = out[(size_t)((t+1)*B_ + row_g + er0    )*H_ + n0 + ec];
            xw1 = out[(size_t)((t+1)*B_ + row_g + er0 + 1)*H_ + n0 + ec];
        }
        // parity-double-buffered partials: t+2's same-parity overwrite is
        // separated from t's read by t+1's __syncthreads.
    }
}

// ---- host --------------------------------------------------------------------
extern "C" void kernel_launch(void* const* d_in, const int* in_sizes, int n_in,
                              void* d_out, int out_size, void* d_ws, size_t ws_size,
                              hipStream_t stream) {
    const float* x    = (const float*)d_in[0];
    const float* h0   = (const float*)d_in[1];
    const float* Wx   = (const float*)d_in[2];
    const float* Wh   = (const float*)d_in[3];
    const float* bias = (const float*)d_in[4];
    float* out = (float*)d_out;

    const size_t nX = (size_t)T_ * B_ * IN_;            // 16,777,216
    const size_t nWx = (size_t)IN_ * H_;                // 524,288
    const size_t hbufB = (size_t)8 * GP * sizeof(u32);  // 512 KB packed ping-pong
    const size_t FULL_NEED = 2*nX*2 + 2*nWx*2 + hbufB;  // ~66.5 MiB
    const size_t SAFE_NEED = hbufB;
    if (ws_size < SAFE_NEED) return;   // cannot run; fail loudly

    bool full = ws_size >= FULL_NEED;
    u16 *xhi = nullptr, *xlo = nullptr, *wthi = nullptr, *wtlo = nullptr;
    u32* hbufP;
    if (full) {
        xhi  = (u16*)d_ws;
        xlo  = xhi + nX;
        wthi = xlo + nX;
        wtlo = wthi + nWx;
        hbufP = (u32*)(wtlo + nWx);
    } else {
        hbufP = (u32*)d_ws;
    }

    // zero hbufP: tag 0 can never validate (tags are 64..127); poison 0xAA = tag 42 safe
    hipMemsetAsync(hbufP, 0, hbufB, stream);
    k_h0<<<HB/256, 256, 0, stream>>>(h0, hbufP);
    if (full) {
        k_split4<<<2048, 256, 0, stream>>>((const float4*)x, xhi, xlo, (int)(nX/4));
        k_tsplit<<<(int)(nWx/256), 256, 0, stream>>>(Wx, wthi, wtlo, IN_, H_);
        k_gemm_xw<<<2048, 256, 0, stream>>>(xhi, xlo, wthi, wtlo, bias, out);
    } else {
        k_gemm_f32<<<dim3(16, 512), 256, 0, stream>>>(x, Wx, bias, out);
    }
    k_scan<<<128, 256, 0, stream>>>(Wh, out, hbufP);
}

// Round 9
// 2400.638 us; speedup vs baseline: 1.2672x; 1.2672x over previous
//
#include <hip/hip_runtime.h>
#include <hip/hip_bf16.h>

// RNN: outs[t] = h_t = tanh(x[t]@Wx + b + h_{t-1}@Wh), T=512,B=64,IN=512,H=1024
//  - split-bf16 (hi+lo) MFMA everywhere (no fp32 MFMA on CDNA4); 3-term product
//  - phase A: xw = x@Wx+b written directly into d_out (overwritten by h_t in place)
//  - scan: persistent wgs, Wh register-resident, self-validating tagged-f32 h
//    (low 7 mantissa bits = epoch tag 64|(t&63); the poll IS the data load).
//  - R1 coherent-h only: 15.5->9.5 us/step. R2 flag barrier: REGRESSED.
//  - R3 self-validating h: ->6.4. R4 XCD-local: DEADLOCK (lesson: polled bytes
//    must use architecturally-coherent ops). R5 swap-RMW+chunk retries: ->5.9.
//  - R6 group-packed col-major layout [g][par][1024k][16r] + LDS bounce: ->4.6.
//  - R7 chunk-pipelined poll: REGRESSED (+0.85/step) -> compute inside the sweep
//    loop delays re-polls; LAST-producer detection is the critical path. Keep
//    the poll loop tight.
//  - R8: 64 wgs x 512 thr (8 waves: 4 kslice x 2 colhalf). 16 producers/group
//    (was 32) -> smaller skew max; col-halves SHARE one LDS h-image -> wg reads
//    h once (chip IC reads halve); each wave polls only HALF a k-slice (8KB,
//    16 chunks) -> sweep drain halves. Two barriers/step bracket LDS hazards
//    (parity dbuf dropped). Poll loop = R6 verbatim.

#define T_ 512
#define B_ 64
#define IN_ 512
#define H_ 1024
constexpr int TBH = T_ * B_ * H_;   // 33,554,432
constexpr int HB  = B_ * H_;        // 65,536
constexpr int GP  = 1024 * 16;      // u32s per (group,parity) packed slice

typedef unsigned short u16;
typedef unsigned int u32;
typedef unsigned long long u64;
typedef __attribute__((ext_vector_type(8))) short short8;   // 8 x bf16 (4 VGPRs)
typedef __attribute__((ext_vector_type(4))) float f32x4;

__device__ __forceinline__ void splitbf(float x, u16& hi, u16& lo) {
    unsigned u = __float_as_uint(x);
    hi = (u16)(u >> 16);                       // truncated bf16 hi
    float r = x - __uint_as_float(u & 0xffff0000u);
    lo = (u16)(__float_as_uint(r) >> 16);      // bf16 of residual; total rel err ~2^-16
}

// ---- prep kernels ------------------------------------------------------------
__global__ void k_split4(const float4* __restrict__ in, u16* __restrict__ hi,
                         u16* __restrict__ lo, int n4) {
    int i = blockIdx.x * blockDim.x + threadIdx.x;
    int stride = gridDim.x * blockDim.x;
    for (; i < n4; i += stride) {
        float4 v = in[i];
        u16 h0,h1,h2,h3,l0,l1,l2,l3;
        splitbf(v.x,h0,l0); splitbf(v.y,h1,l1); splitbf(v.z,h2,l2); splitbf(v.w,h3,l3);
        uint2 hv, lv;
        hv.x = (unsigned)h0 | ((unsigned)h1 << 16);
        hv.y = (unsigned)h2 | ((unsigned)h3 << 16);
        lv.x = (unsigned)l0 | ((unsigned)l1 << 16);
        lv.y = (unsigned)l2 | ((unsigned)l3 << 16);
        *(uint2*)&hi[4*i] = hv;
        *(uint2*)&lo[4*i] = lv;
    }
}

// src [K][N] fp32 -> dst [N][K] bf16 hi/lo (transposed for B-fragment reads)
__global__ void k_tsplit(const float* __restrict__ src, u16* __restrict__ hi,
                         u16* __restrict__ lo, int K, int N) {
    int id = blockIdx.x * 256 + threadIdx.x;
    if (id >= K * N) return;
    int k = id / N, n = id % N;
    u16 h, l; splitbf(src[id], h, l);
    hi[n*K + k] = h; lo[n*K + k] = l;
}

// h0 fp32 [B][H] -> packed tagged-f32 parity-1 (read at t=0, expects tag 127)
__global__ void k_h0(const float* __restrict__ h0, u32* __restrict__ hbufP) {
    int id = blockIdx.x * 256 + threadIdx.x;
    if (id >= HB) return;
    int b = id >> 10, k = id & 1023;
    u32 u = __float_as_uint(h0[id]);
    hbufP[(size_t)((b>>4)*2 + 1)*GP + k*16 + (b & 15)] = (u & 0xFFFFFF80u) | 127u;
}

// ---- phase A: xw = x@Wx + b, split-bf16 MFMA, 128x128 tile, frags from global -
__launch_bounds__(256, 2)
__global__ void k_gemm_xw(const u16* __restrict__ xhi, const u16* __restrict__ xlo,
                          const u16* __restrict__ wthi, const u16* __restrict__ wtlo,
                          const float* __restrict__ bias, float* __restrict__ out) {
    int bid = blockIdx.x;
    int mi = bid >> 3, ni = bid & 7;
    int m0 = mi * 128, n0 = ni * 128;
    int wave = threadIdx.x >> 6, lane = threadIdx.x & 63;
    int wr = wave >> 1, wc = wave & 1;
    int lrow = lane & 15, lk8 = (lane >> 4) * 8;
    const int rowb = m0 + wr*64 + lrow;   // A row for this lane
    const int colb = n0 + wc*64 + lrow;   // B col for this lane
    f32x4 acc[4][4] = {};
    for (int kt = 0; kt < 16; ++kt) {
        int kb = kt*32 + lk8;
        short8 ah[4], al[4], bh[4], bl[4];
#pragma unroll
        for (int mt = 0; mt < 4; ++mt) {
            ah[mt] = *(const short8*)&xhi[(size_t)(rowb + mt*16)*IN_ + kb];
            al[mt] = *(const short8*)&xlo[(size_t)(rowb + mt*16)*IN_ + kb];
        }
#pragma unroll
        for (int nt = 0; nt < 4; ++nt) {
            bh[nt] = *(const short8*)&wthi[(size_t)(colb + nt*16)*IN_ + kb];
            bl[nt] = *(const short8*)&wtlo[(size_t)(colb + nt*16)*IN_ + kb];
        }
#pragma unroll
        for (int mt = 0; mt < 4; ++mt)
#pragma unroll
            for (int nt = 0; nt < 4; ++nt) {
                acc[mt][nt] = __builtin_amdgcn_mfma_f32_16x16x32_bf16(ah[mt], bh[nt], acc[mt][nt], 0,0,0);
                acc[mt][nt] = __builtin_amdgcn_mfma_f32_16x16x32_bf16(ah[mt], bl[nt], acc[mt][nt], 0,0,0);
                acc[mt][nt] = __builtin_amdgcn_mfma_f32_16x16x32_bf16(al[mt], bh[nt], acc[mt][nt], 0,0,0);
            }
    }
    // epilogue: D layout col=lane&15, row=4*(lane>>4)+reg
    int orow0 = m0 + wr*64 + 4*(lane >> 4);
#pragma unroll
    for (int nt = 0; nt < 4; ++nt) {
        int col = n0 + wc*64 + nt*16 + (lane & 15);
        float bv = bias[col];
#pragma unroll
        for (int mt = 0; mt < 4; ++mt)
#pragma unroll
            for (int r = 0; r < 4; ++r)
                out[(size_t)(orow0 + mt*16 + r)*H_ + col] = acc[mt][nt][r] + bv;
    }
}

// ---- phase A fallback (fp32 vector) if ws too small for split buffers --------
__global__ void k_gemm_f32(const float* __restrict__ A, const float* __restrict__ Bw,
                           const float* __restrict__ bias, float* __restrict__ out) {
    __shared__ float As[32][65];  // [k][m]
    __shared__ float Bs[32][65];  // [k][n]
    int n0 = blockIdx.x * 64, m0 = blockIdx.y * 64;
    int tid = threadIdx.x;
    int tr = tid >> 4, tc = tid & 15;
    float acc[4][4] = {};
    for (int kc = 0; kc < IN_; kc += 32) {
#pragma unroll
        for (int it = 0; it < 8; ++it) {
            int id = tid + 256*it;
            int k = id & 31, m = id >> 5;
            As[k][m] = A[(size_t)(m0 + m)*IN_ + kc + k];
        }
#pragma unroll
        for (int it = 0; it < 8; ++it) {
            int id = tid + 256*it;
            int n = id & 63, kk = id >> 6;
            Bs[kk][n] = Bw[(size_t)(kc + kk)*H_ + n0 + n];
        }
        __syncthreads();
#pragma unroll
        for (int kk = 0; kk < 32; ++kk) {
            float a[4], b[4];
#pragma unroll
            for (int i = 0; i < 4; ++i) a[i] = As[kk][tr*4+i];
#pragma unroll
            for (int j = 0; j < 4; ++j) b[j] = Bs[kk][tc*4+j];
#pragma unroll
            for (int i = 0; i < 4; ++i)
#pragma unroll
                for (int j = 0; j < 4; ++j) acc[i][j] += a[i]*b[j];
        }
        __syncthreads();
    }
#pragma unroll
    for (int i = 0; i < 4; ++i)
#pragma unroll
        for (int j = 0; j < 4; ++j)
            out[(size_t)(m0 + tr*4 + i)*H_ + n0 + tc*4 + j] = acc[i][j] + bias[n0 + tc*4 + j];
}

// ---- scan: 64 wgs x 512 thr, shared LDS h-image, half-slice polls ------------
__launch_bounds__(512, 1)
__global__ void k_scan(const float* __restrict__ wh,   // [H][H] fp32 (k-major)
                       float* __restrict__ out,        // [T][B][H] xw in / h out, + h_last tail
                       u32* __restrict__ hbufP) {      // [4 g][2 par][1024 k][16 r] tagged f32
    int bid = blockIdx.x;
    int g = bid >> 4, cw = bid & 15;      // group, col-wg (64 cols each)
    int row_g = g * 16;
    int wave = threadIdx.x >> 6, lane = threadIdx.x & 63;
    int ks = wave & 3, ch = wave >> 2;    // k-slice (256 wide), col-half (32 wide)
    int n0 = cw*64 + ch*32;               // this wave's first col
    int lrow = lane & 15, lk8 = (lane >> 4) * 8;
    __shared__ float partial[8 * 16 * 33];   // [ch*4+ks][row][col(+pad)]
    __shared__ float hx[16 * 1030];          // [row][k] shared h image, stride 1030

    // Load Wh fragments ONCE: this wave covers k in [ks*256,+256), cols [n0,+32)
    short8 bh[2][8], bl[2][8];
#pragma unroll
    for (int nt = 0; nt < 2; ++nt) {
        int col = n0 + nt*16 + lrow;
#pragma unroll
        for (int kt = 0; kt < 8; ++kt) {
            int kbase = ks*256 + kt*32 + lk8;
            short8 h8, l8;
#pragma unroll
            for (int j = 0; j < 8; ++j) {
                u16 hh, ll; splitbf(wh[(size_t)(kbase + j)*H_ + col], hh, ll);
                h8[j] = (short)hh; l8[j] = (short)ll;
            }
            bh[nt][kt] = h8; bl[nt][kt] = l8;
        }
    }

    // epilogue mapping: thread = (col ec 0..63, row-pair er0)
    const int ec  = threadIdx.x >> 3;        // 0..63 wg-local col
    const int er0 = (threadIdx.x & 7) * 2;   // 0,2,..,14 group-local row
    const int ech = ec >> 5;                 // which col-half for partial reads
    const int ecl = ec & 31;                 // col within half

    // prefetch xw for t=0
    float xw0 = out[(size_t)(row_g + er0    )*H_ + cw*64 + ec];
    float xw1 = out[(size_t)(row_g + er0 + 1)*H_ + cw*64 + ec];

    // poll/bounce indexing: this wave polls k in [ks*256 + ch*128, +128) x 16 r
    // = 16 chunks of 8k; u64 #(i*64+lane): k_local = i*8+(lane>>3), rows 2*(lane&7),+1
    const int bcol = ks*256 + ch*128 + (lane >> 3);
    const int brow = 2 * (lane & 7);

    for (int t = 0; t < T_; ++t) {
        const u32 want = 64u | (u32)((t - 1) & 63);
        const u64 want64 = ((u64)want << 32) | (u64)want;
        const int par = t & 1;
        const u64* sb = (const u64*)(hbufP + (size_t)(g*2 + ((t+1)&1))*GP)
                        + ks*2048 + ch*1024;

        // ---- tight self-validating poll of this wave's 8KB half-slice ----
        u64 raw[16];
        u32 pend = 0xFFFFu;
        for (;;) {
#pragma unroll
            for (int i = 0; i < 16; ++i)
                if (pend & (1u << i))
                    raw[i] = __hip_atomic_load(sb + i*64 + lane, __ATOMIC_RELAXED,
                                               __HIP_MEMORY_SCOPE_AGENT);
            u32 np = 0;
#pragma unroll
            for (int i = 0; i < 16; ++i)
                if (pend & (1u << i)) {
                    u64 bad = (raw[i] ^ want64) & 0x0000007F0000007FULL;
                    if (__any(bad != 0)) np |= 1u << i;
                }
            pend = np;
            if (pend == 0) break;
            __builtin_amdgcn_s_sleep(1);
        }
        // bounce to shared hx (disjoint region per wave)
#pragma unroll
        for (int i = 0; i < 16; ++i) {
            int col = bcol + i*8;
            hx[brow*1030 + col]     = __uint_as_float((u32)raw[i]);
            hx[(brow+1)*1030 + col] = __uint_as_float((u32)(raw[i] >> 32));
        }
        __syncthreads();   // hx complete (all 8 half-slices published)

        // ---- fragments from hx + convert + MFMA (parity-split chains) ----
        f32x4 acc[2][2] = {};
#pragma unroll
        for (int kt = 0; kt < 8; ++kt) {
            int p = kt & 1;
            short8 ah, al;
            int cb = lrow*1030 + ks*256 + kt*32 + lk8;
#pragma unroll
            for (int j = 0; j < 8; ++j) {
                u32 bits = __float_as_uint(hx[cb + j]);
                ah[j] = (short)(bits >> 16);
                float r = __uint_as_float(bits & 0xFFFFFF80u)
                        - __uint_as_float(bits & 0xFFFF0000u);
                al[j] = (short)(__float_as_uint(r) >> 16);
            }
#pragma unroll
            for (int nt = 0; nt < 2; ++nt) {
                acc[nt][p] = __builtin_amdgcn_mfma_f32_16x16x32_bf16(ah, bh[nt][kt], acc[nt][p], 0,0,0);
                acc[nt][p] = __builtin_amdgcn_mfma_f32_16x16x32_bf16(ah, bl[nt][kt], acc[nt][p], 0,0,0);
                acc[nt][p] = __builtin_amdgcn_mfma_f32_16x16x32_bf16(al, bh[nt][kt], acc[nt][p], 0,0,0);
            }
        }
        // K-partials: [ch*4+ks][row][col], row=4*(lane>>4)+r, col=nt*16+lrow
        {
            int r0 = 4 * (lane >> 4);
#pragma unroll
            for (int nt = 0; nt < 2; ++nt) {
                int c = nt*16 + lrow;
#pragma unroll
                for (int r = 0; r < 4; ++r)
                    partial[((ch*4 + ks)*16 + r0 + r)*33 + c] = acc[nt][0][r] + acc[nt][1][r];
            }
        }
        __syncthreads();
        // ---- reduce + tanh; h-store FIRST (exchange-critical), then out ----
        {
            float s0 = xw0, s1 = xw1;
#pragma unroll
            for (int w = 0; w < 4; ++w) {
                s0 += partial[((ech*4 + w)*16 + er0    )*33 + ecl];
                s1 += partial[((ech*4 + w)*16 + er0 + 1)*33 + ecl];
            }
            float y0 = tanhf(s0), y1 = tanhf(s1);
            const u32 tagt = 64u | (u32)(t & 63);
            u32 b0 = (__float_as_uint(y0) & 0xFFFFFF80u) | tagt;
            u32 b1 = (__float_as_uint(y1) & 0xFFFFFF80u) | tagt;
            // packed [col][row-pair] -> one contiguous u64 swap (RMW at coherence pt)
            u32* hnb = hbufP + (size_t)(g*2 + par)*GP + (cw*64 + ec)*16 + er0;
            (void)__hip_atomic_exchange((u64*)hnb, ((u64)b1 << 32) | (u64)b0,
                                        __ATOMIC_RELAXED, __HIP_MEMORY_SCOPE_AGENT);
            int gb0 = row_g + er0;
            out[(size_t)(t*B_ + gb0    )*H_ + cw*64 + ec] = y0;
            out[(size_t)(t*B_ + gb0 + 1)*H_ + cw*64 + ec] = y1;
            if (t == T_-1) {
                out[(size_t)TBH + (size_t)gb0*H_ + cw*64 + ec] = y0;
                out[(size_t)TBH + (size_t)(gb0+1)*H_ + cw*64 + ec] = y1;
            }
        }
        // prefetch next xw (latency hides under next step's h polling)
        if (t + 1 < T_) {
            xw0 = out[(size_t)((t+1)*B_ + row_g + er0    )*H_ + cw*64 + ec];
            xw1 = out[(size_t)((t+1)*B_ + row_g + er0 + 1)*H_ + cw*64 + ec];
        }
        // LDS hazards: hx writes(t+1) are after this thread's barrier2(t) and
        // readers finished hx reads before barrier2(t); partial writes(t+1)
        // are after barrier1(t+1), readers read before reaching barrier1(t+1).
    }
}

// ---- host --------------------------------------------------------------------
extern "C" void kernel_launch(void* const* d_in, const int* in_sizes, int n_in,
                              void* d_out, int out_size, void* d_ws, size_t ws_size,
                              hipStream_t stream) {
    const float* x    = (const float*)d_in[0];
    const float* h0   = (const float*)d_in[1];
    const float* Wx   = (const float*)d_in[2];
    const float* Wh   = (const float*)d_in[3];
    const float* bias = (const float*)d_in[4];
    float* out = (float*)d_out;

    const size_t nX = (size_t)T_ * B_ * IN_;            // 16,777,216
    const size_t nWx = (size_t)IN_ * H_;                // 524,288
    const size_t hbufB = (size_t)8 * GP * sizeof(u32);  // 512 KB packed ping-pong
    const size_t FULL_NEED = 2*nX*2 + 2*nWx*2 + hbufB;  // ~66.5 MiB
    const size_t SAFE_NEED = hbufB;
    if (ws_size < SAFE_NEED) return;   // cannot run; fail loudly

    bool full = ws_size >= FULL_NEED;
    u16 *xhi = nullptr, *xlo = nullptr, *wthi = nullptr, *wtlo = nullptr;
    u32* hbufP;
    if (full) {
        xhi  = (u16*)d_ws;
        xlo  = xhi + nX;
        wthi = xlo + nX;
        wtlo = wthi + nWx;
        hbufP = (u32*)(wtlo + nWx);
    } else {
        hbufP = (u32*)d_ws;
    }

    // zero hbufP: tag 0 can never validate (tags are 64..127); poison 0xAA = tag 42 safe
    hipMemsetAsync(hbufP, 0, hbufB, stream);
    k_h0<<<HB/256, 256, 0, stream>>>(h0, hbufP);
    if (full) {
        k_split4<<<2048, 256, 0, stream>>>((const float4*)x, xhi, xlo, (int)(nX/4));
        k_tsplit<<<(int)(nWx/256), 256, 0, stream>>>(Wx, wthi, wtlo, IN_, H_);
        k_gemm_xw<<<2048, 256, 0, stream>>>(xhi, xlo, wthi, wtlo, bias, out);
    } else {
        k_gemm_f32<<<dim3(16, 512), 256, 0, stream>>>(x, Wx, bias, out);
    }
    k_scan<<<64, 512, 0, stream>>>(Wh, out, hbufP);
}

// Round 10
// 2110.744 us; speedup vs baseline: 1.4412x; 1.1373x over previous
//
#include <hip/hip_runtime.h>
#include <hip/hip_bf16.h>

// RNN: outs[t] = h_t = tanh(x[t]@Wx + b + h_{t-1}@Wh), T=512,B=64,IN=512,H=1024
//  - split-bf16 (hi+lo) MFMA everywhere (no fp32 MFMA on CDNA4); 3-term product
//  - phase A: xw = x@Wx+b written directly into d_out (overwritten by h_t in place)
//  - scan: persistent wgs, Wh register-resident, self-validating tagged-f32 h
//    (low 7 mantissa bits = epoch tag 64|(t&63); the poll IS the data load).
//  - R1 coherent-h only: 15.5->9.5 us/step. R2 flag barrier: REGRESSED.
//  - R3 self-validating h: ->6.4. R4 XCD-local: DEADLOCK (lesson: polled bytes
//    must use architecturally-coherent ops). R5 swap-RMW+chunk retries: ->5.9.
//  - R6 group-packed col-major layout + LDS bounce: ->4.6.
//  - R7 compute inside poll loop: REGRESSED -> keep poll tight.
//  - R8 64wg x 512thr, shared LDS h-image, half-slice polls: ->4.16.
//  - R9: (a) 8 groups x 8 ROWS x 16 wgs: each wg polls 32KB (8 loads/wave
//    sweep, half of R8) via row-duplicated M=8 MFMA (outputs 8-15 discarded);
//    (b) EARLY-ISSUE first poll sweep before barrier2: its IC flight overlaps
//    barrier + epilogue + loop-back; validation at next loop top. Producers
//    per group stay 16 (VGPR-locked: Wh frags = 128 VGPR/wave ceiling).

#define T_ 512
#define B_ 64
#define IN_ 512
#define H_ 1024
constexpr int TBH = T_ * B_ * H_;   // 33,554,432
constexpr int HB  = B_ * H_;        // 65,536
constexpr int GP8 = 1024 * 8;       // u32s per (group,parity) packed slice (8 rows)

typedef unsigned short u16;
typedef unsigned int u32;
typedef unsigned long long u64;
typedef __attribute__((ext_vector_type(8))) short short8;   // 8 x bf16 (4 VGPRs)
typedef __attribute__((ext_vector_type(4))) float f32x4;

__device__ __forceinline__ void splitbf(float x, u16& hi, u16& lo) {
    unsigned u = __float_as_uint(x);
    hi = (u16)(u >> 16);                       // truncated bf16 hi
    float r = x - __uint_as_float(u & 0xffff0000u);
    lo = (u16)(__float_as_uint(r) >> 16);      // bf16 of residual; total rel err ~2^-16
}

// ---- prep kernels ------------------------------------------------------------
__global__ void k_split4(const float4* __restrict__ in, u16* __restrict__ hi,
                         u16* __restrict__ lo, int n4) {
    int i = blockIdx.x * blockDim.x + threadIdx.x;
    int stride = gridDim.x * blockDim.x;
    for (; i < n4; i += stride) {
        float4 v = in[i];
        u16 h0,h1,h2,h3,l0,l1,l2,l3;
        splitbf(v.x,h0,l0); splitbf(v.y,h1,l1); splitbf(v.z,h2,l2); splitbf(v.w,h3,l3);
        uint2 hv, lv;
        hv.x = (unsigned)h0 | ((unsigned)h1 << 16);
        hv.y = (unsigned)h2 | ((unsigned)h3 << 16);
        lv.x = (unsigned)l0 | ((unsigned)l1 << 16);
        lv.y = (unsigned)l2 | ((unsigned)l3 << 16);
        *(uint2*)&hi[4*i] = hv;
        *(uint2*)&lo[4*i] = lv;
    }
}

// src [K][N] fp32 -> dst [N][K] bf16 hi/lo (transposed for B-fragment reads)
__global__ void k_tsplit(const float* __restrict__ src, u16* __restrict__ hi,
                         u16* __restrict__ lo, int K, int N) {
    int id = blockIdx.x * 256 + threadIdx.x;
    if (id >= K * N) return;
    int k = id / N, n = id % N;
    u16 h, l; splitbf(src[id], h, l);
    hi[n*K + k] = h; lo[n*K + k] = l;
}

// h0 fp32 [B][H] -> packed tagged-f32 parity-1 (read at t=0, expects tag 127)
__global__ void k_h0(const float* __restrict__ h0, u32* __restrict__ hbufP) {
    int id = blockIdx.x * 256 + threadIdx.x;
    if (id >= HB) return;
    int b = id >> 10, k = id & 1023;
    u32 u = __float_as_uint(h0[id]);
    hbufP[(size_t)((b>>3)*2 + 1)*GP8 + k*8 + (b & 7)] = (u & 0xFFFFFF80u) | 127u;
}

// ---- phase A: xw = x@Wx + b, split-bf16 MFMA, 128x128 tile, frags from global -
__launch_bounds__(256, 2)
__global__ void k_gemm_xw(const u16* __restrict__ xhi, const u16* __restrict__ xlo,
                          const u16* __restrict__ wthi, const u16* __restrict__ wtlo,
                          const float* __restrict__ bias, float* __restrict__ out) {
    int bid = blockIdx.x;
    int mi = bid >> 3, ni = bid & 7;
    int m0 = mi * 128, n0 = ni * 128;
    int wave = threadIdx.x >> 6, lane = threadIdx.x & 63;
    int wr = wave >> 1, wc = wave & 1;
    int lrow = lane & 15, lk8 = (lane >> 4) * 8;
    const int rowb = m0 + wr*64 + lrow;   // A row for this lane
    const int colb = n0 + wc*64 + lrow;   // B col for this lane
    f32x4 acc[4][4] = {};
    for (int kt = 0; kt < 16; ++kt) {
        int kb = kt*32 + lk8;
        short8 ah[4], al[4], bh[4], bl[4];
#pragma unroll
        for (int mt = 0; mt < 4; ++mt) {
            ah[mt] = *(const short8*)&xhi[(size_t)(rowb + mt*16)*IN_ + kb];
            al[mt] = *(const short8*)&xlo[(size_t)(rowb + mt*16)*IN_ + kb];
        }
#pragma unroll
        for (int nt = 0; nt < 4; ++nt) {
            bh[nt] = *(const short8*)&wthi[(size_t)(colb + nt*16)*IN_ + kb];
            bl[nt] = *(const short8*)&wtlo[(size_t)(colb + nt*16)*IN_ + kb];
        }
#pragma unroll
        for (int mt = 0; mt < 4; ++mt)
#pragma unroll
            for (int nt = 0; nt < 4; ++nt) {
                acc[mt][nt] = __builtin_amdgcn_mfma_f32_16x16x32_bf16(ah[mt], bh[nt], acc[mt][nt], 0,0,0);
                acc[mt][nt] = __builtin_amdgcn_mfma_f32_16x16x32_bf16(ah[mt], bl[nt], acc[mt][nt], 0,0,0);
                acc[mt][nt] = __builtin_amdgcn_mfma_f32_16x16x32_bf16(al[mt], bh[nt], acc[mt][nt], 0,0,0);
            }
    }
    // epilogue: D layout col=lane&15, row=4*(lane>>4)+reg
    int orow0 = m0 + wr*64 + 4*(lane >> 4);
#pragma unroll
    for (int nt = 0; nt < 4; ++nt) {
        int col = n0 + wc*64 + nt*16 + (lane & 15);
        float bv = bias[col];
#pragma unroll
        for (int mt = 0; mt < 4; ++mt)
#pragma unroll
            for (int r = 0; r < 4; ++r)
                out[(size_t)(orow0 + mt*16 + r)*H_ + col] = acc[mt][nt][r] + bv;
    }
}

// ---- phase A fallback (fp32 vector) if ws too small for split buffers --------
__global__ void k_gemm_f32(const float* __restrict__ A, const float* __restrict__ Bw,
                           const float* __restrict__ bias, float* __restrict__ out) {
    __shared__ float As[32][65];  // [k][m]
    __shared__ float Bs[32][65];  // [k][n]
    int n0 = blockIdx.x * 64, m0 = blockIdx.y * 64;
    int tid = threadIdx.x;
    int tr = tid >> 4, tc = tid & 15;
    float acc[4][4] = {};
    for (int kc = 0; kc < IN_; kc += 32) {
#pragma unroll
        for (int it = 0; it < 8; ++it) {
            int id = tid + 256*it;
            int k = id & 31, m = id >> 5;
            As[k][m] = A[(size_t)(m0 + m)*IN_ + kc + k];
        }
#pragma unroll
        for (int it = 0; it < 8; ++it) {
            int id = tid + 256*it;
            int n = id & 63, kk = id >> 6;
            Bs[kk][n] = Bw[(size_t)(kc + kk)*H_ + n0 + n];
        }
        __syncthreads();
#pragma unroll
        for (int kk = 0; kk < 32; ++kk) {
            float a[4], b[4];
#pragma unroll
            for (int i = 0; i < 4; ++i) a[i] = As[kk][tr*4+i];
#pragma unroll
            for (int j = 0; j < 4; ++j) b[j] = Bs[kk][tc*4+j];
#pragma unroll
            for (int i = 0; i < 4; ++i)
#pragma unroll
                for (int j = 0; j < 4; ++j) acc[i][j] += a[i]*b[j];
        }
        __syncthreads();
    }
#pragma unroll
    for (int i = 0; i < 4; ++i)
#pragma unroll
        for (int j = 0; j < 4; ++j)
            out[(size_t)(m0 + tr*4 + i)*H_ + n0 + tc*4 + j] = acc[i][j] + bias[n0 + tc*4 + j];
}

// ---- scan: 128 wgs x 512 thr, 8-row groups, early-issued poll sweeps ---------
__launch_bounds__(512, 1)
__global__ void k_scan(const float* __restrict__ wh,   // [H][H] fp32 (k-major)
                       float* __restrict__ out,        // [T][B][H] xw in / h out, + h_last tail
                       u32* __restrict__ hbufP) {      // [8 g][2 par][1024 k][8 r] tagged f32
    int bid = blockIdx.x;
    int g = bid >> 4, cw = bid & 15;      // group (8 rows), col-wg (64 cols)
    int row_g = g * 8;
    int wave = threadIdx.x >> 6, lane = threadIdx.x & 63;
    int ks = wave & 3, ch = wave >> 2;    // k-slice (256 wide), col-half (32 wide)
    int n0 = cw*64 + ch*32;               // this wave's first col
    int lrow = lane & 15, lk8 = (lane >> 4) * 8;
    __shared__ float partial[8 * 8 * 33];    // [ch*4+ks][row8][col(+pad)]
    __shared__ float hx[8 * 1030];           // [row8][k] shared h image, stride 1030

    // Load Wh fragments ONCE: this wave covers k in [ks*256,+256), cols [n0,+32)
    short8 bh[2][8], bl[2][8];
#pragma unroll
    for (int nt = 0; nt < 2; ++nt) {
        int col = n0 + nt*16 + lrow;
#pragma unroll
        for (int kt = 0; kt < 8; ++kt) {
            int kbase = ks*256 + kt*32 + lk8;
            short8 h8, l8;
#pragma unroll
            for (int j = 0; j < 8; ++j) {
                u16 hh, ll; splitbf(wh[(size_t)(kbase + j)*H_ + col], hh, ll);
                h8[j] = (short)hh; l8[j] = (short)ll;
            }
            bh[nt][kt] = h8; bl[nt][kt] = l8;
        }
    }

    // epilogue mapping: threads 0..255: ec = col 0..63, er0 = row-pair base
    const int ec  = threadIdx.x >> 2;        // 0..127 (only <64 used via tid<256)
    const int er0 = (threadIdx.x & 3) * 2;   // 0,2,4,6
    const bool epi = (threadIdx.x < 256);
    const int ech = (ec >> 5) & 1;           // col-half for partial reads
    const int ecl = ec & 31;

    // prefetch xw for t=0
    float xw0 = 0.f, xw1 = 0.f;
    if (epi) {
        xw0 = out[(size_t)(row_g + er0    )*H_ + cw*64 + ec];
        xw1 = out[(size_t)(row_g + er0 + 1)*H_ + cw*64 + ec];
    }

    // poll/bounce indexing: wave polls k in [wave*128,+128) x 8 rows = 4KB.
    // u64 #(i*64+lane): k = wave*128 + i*16 + (lane>>2), rows 2*(lane&3), +1.
    const int bcol = wave*128 + (lane >> 2);
    const int brow = 2 * (lane & 3);

    // ---- pre-loop: issue first sweep for t=0 (parity 1, written by k_h0) ----
    u64 raw[8];
    u32 pend = 0xFFu;
    {
        const u64* sb = (const u64*)(hbufP + (size_t)(g*2 + 1)*GP8) + wave*512;
#pragma unroll
        for (int i = 0; i < 8; ++i)
            raw[i] = __hip_atomic_load(sb + i*64 + lane, __ATOMIC_RELAXED,
                                       __HIP_MEMORY_SCOPE_AGENT);
    }

    for (int t = 0; t < T_; ++t) {
        const u32 want = 64u | (u32)((t - 1) & 63);
        const u64 want64 = ((u64)want << 32) | (u64)want;
        const int par = t & 1;
        const u64* sb = (const u64*)(hbufP + (size_t)(g*2 + ((t+1)&1))*GP8) + wave*512;

        // ---- tight validate/reload poll (first sweep already in flight) ----
        for (;;) {
            u32 np = 0;
#pragma unroll
            for (int i = 0; i < 8; ++i)
                if (pend & (1u << i)) {
                    u64 bad = (raw[i] ^ want64) & 0x0000007F0000007FULL;
                    if (__any(bad != 0)) np |= 1u << i;
                }
            u32 progress = pend ^ np;
            pend = np;
            if (pend == 0) break;
            if (!progress) __builtin_amdgcn_s_sleep(1);
#pragma unroll
            for (int i = 0; i < 8; ++i)
                if (pend & (1u << i))
                    raw[i] = __hip_atomic_load(sb + i*64 + lane, __ATOMIC_RELAXED,
                                               __HIP_MEMORY_SCOPE_AGENT);
        }
        // bounce to shared hx (disjoint region per wave)
#pragma unroll
        for (int i = 0; i < 8; ++i) {
            int col = bcol + i*16;
            hx[brow*1030 + col]     = __uint_as_float((u32)raw[i]);
            hx[(brow+1)*1030 + col] = __uint_as_float((u32)(raw[i] >> 32));
        }
        __syncthreads();   // hx complete (all 8 slices published)

        // ---- fragments from hx (rows duplicated for M=8) + convert + MFMA ----
        f32x4 acc[2][2] = {};
#pragma unroll
        for (int kt = 0; kt < 8; ++kt) {
            int p = kt & 1;
            short8 ah, al;
            int cb = (lrow & 7)*1030 + ks*256 + kt*32 + lk8;
#pragma unroll
            for (int j = 0; j < 8; ++j) {
                u32 bits = __float_as_uint(hx[cb + j]);
                ah[j] = (short)(bits >> 16);
                float r = __uint_as_float(bits & 0xFFFFFF80u)
                        - __uint_as_float(bits & 0xFFFF0000u);
                al[j] = (short)(__float_as_uint(r) >> 16);
            }
#pragma unroll
            for (int nt = 0; nt < 2; ++nt) {
                acc[nt][p] = __builtin_amdgcn_mfma_f32_16x16x32_bf16(ah, bh[nt][kt], acc[nt][p], 0,0,0);
                acc[nt][p] = __builtin_amdgcn_mfma_f32_16x16x32_bf16(ah, bl[nt][kt], acc[nt][p], 0,0,0);
                acc[nt][p] = __builtin_amdgcn_mfma_f32_16x16x32_bf16(al, bh[nt][kt], acc[nt][p], 0,0,0);
            }
        }
        // K-partials (rows 0..7 live in lanes 0..31): [ch*4+ks][row8][col]
        if (lane < 32) {
            int r0 = 4 * (lane >> 4);
#pragma unroll
            for (int nt = 0; nt < 2; ++nt) {
                int c = nt*16 + lrow;
#pragma unroll
                for (int r = 0; r < 4; ++r)
                    partial[((ch*4 + ks)*8 + r0 + r)*33 + c] = acc[nt][0][r] + acc[nt][1][r];
            }
        }

        // ---- EARLY-ISSUE next step's first sweep (overlaps barrier+epilogue) ----
        if (t + 1 < T_) {
            const u64* sbn = (const u64*)(hbufP + (size_t)(g*2 + par)*GP8) + wave*512;
#pragma unroll
            for (int i = 0; i < 8; ++i)
                raw[i] = __hip_atomic_load(sbn + i*64 + lane, __ATOMIC_RELAXED,
                                           __HIP_MEMORY_SCOPE_AGENT);
            pend = 0xFFu;
        }

        __syncthreads();
        // ---- reduce + tanh; h-store FIRST (exchange-critical), then out ----
        if (epi) {
            float s0 = xw0, s1 = xw1;
#pragma unroll
            for (int w = 0; w < 4; ++w) {
                s0 += partial[((ech*4 + w)*8 + er0    )*33 + ecl];
                s1 += partial[((ech*4 + w)*8 + er0 + 1)*33 + ecl];
            }
            float y0 = tanhf(s0), y1 = tanhf(s1);
            const u32 tagt = 64u | (u32)(t & 63);
            u32 b0 = (__float_as_uint(y0) & 0xFFFFFF80u) | tagt;
            u32 b1 = (__float_as_uint(y1) & 0xFFFFFF80u) | tagt;
            // packed [col][row-pair] -> one contiguous u64 swap (RMW at coherence pt)
            u32* hnb = hbufP + (size_t)(g*2 + par)*GP8 + (cw*64 + ec)*8 + er0;
            (void)__hip_atomic_exchange((u64*)hnb, ((u64)b1 << 32) | (u64)b0,
                                        __ATOMIC_RELAXED, __HIP_MEMORY_SCOPE_AGENT);
            int gb0 = row_g + er0;
            out[(size_t)(t*B_ + gb0    )*H_ + cw*64 + ec] = y0;
            out[(size_t)(t*B_ + gb0 + 1)*H_ + cw*64 + ec] = y1;
            if (t == T_-1) {
                out[(size_t)TBH + (size_t)gb0*H_ + cw*64 + ec] = y0;
                out[(size_t)TBH + (size_t)(gb0+1)*H_ + cw*64 + ec] = y1;
            }
            // prefetch next xw (latency hides under next step's h polling)
            if (t + 1 < T_) {
                xw0 = out[(size_t)((t+1)*B_ + gb0    )*H_ + cw*64 + ec];
                xw1 = out[(size_t)((t+1)*B_ + gb0 + 1)*H_ + cw*64 + ec];
            }
        }
        // LDS hazards: hx/partial writes of t+1 happen after barrier1(t+1);
        // all reads of t's data complete before this thread leaves its barriers.
    }
}

// ---- host --------------------------------------------------------------------
extern "C" void kernel_launch(void* const* d_in, const int* in_sizes, int n_in,
                              void* d_out, int out_size, void* d_ws, size_t ws_size,
                              hipStream_t stream) {
    const float* x    = (const float*)d_in[0];
    const float* h0   = (const float*)d_in[1];
    const float* Wx   = (const float*)d_in[2];
    const float* Wh   = (const float*)d_in[3];
    const float* bias = (const float*)d_in[4];
    float* out = (float*)d_out;

    const size_t nX = (size_t)T_ * B_ * IN_;             // 16,777,216
    const size_t nWx = (size_t)IN_ * H_;                 // 524,288
    const size_t hbufB = (size_t)16 * GP8 * sizeof(u32); // 512 KB packed ping-pong
    const size_t FULL_NEED = 2*nX*2 + 2*nWx*2 + hbufB;   // ~66.5 MiB
    const size_t SAFE_NEED = hbufB;
    if (ws_size < SAFE_NEED) return;   // cannot run; fail loudly

    bool full = ws_size >= FULL_NEED;
    u16 *xhi = nullptr, *xlo = nullptr, *wthi = nullptr, *wtlo = nullptr;
    u32* hbufP;
    if (full) {
        xhi  = (u16*)d_ws;
        xlo  = xhi + nX;
        wthi = xlo + nX;
        wtlo = wthi + nWx;
        hbufP = (u32*)(wtlo + nWx);
    } else {
        hbufP = (u32*)d_ws;
    }

    // zero hbufP: tag 0 can never validate (tags are 64..127); poison 0xAA = tag 42 safe
    hipMemsetAsync(hbufP, 0, hbufB, stream);
    k_h0<<<HB/256, 256, 0, stream>>>(h0, hbufP);
    if (full) {
        k_split4<<<2048, 256, 0, stream>>>((const float4*)x, xhi, xlo, (int)(nX/4));
        k_tsplit<<<(int)(nWx/256), 256, 0, stream>>>(Wx, wthi, wtlo, IN_, H_);
        k_gemm_xw<<<2048, 256, 0, stream>>>(xhi, xlo, wthi, wtlo, bias, out);
    } else {
        k_gemm_f32<<<dim3(16, 512), 256, 0, stream>>>(x, Wx, bias, out);
    }
    k_scan<<<128, 512, 0, stream>>>(Wh, out, hbufP);
}